// Round 5
// baseline (393.869 us; speedup 1.0000x reference)
//
#include <hip/hip_runtime.h>
#include <hip/hip_bf16.h>
#include <math.h>

typedef __hip_bfloat16 bf16;

// dtype: inputs are f32 (measured round 3), but keep runtime detect via the
// first 32-bit word of a ones-vector: f32 -> 0x3F800000, bf16 -> 0x3F803F80.
__device__ __forceinline__ bool detect_bf16(const void* ones_vec) {
  return ((const unsigned int*)ones_vec)[0] == 0x3F803F80u;
}
__device__ __forceinline__ float ldf(const void* p, long idx, bool isb) {
  if (isb) return __bfloat162float(((const bf16*)p)[idx]);
  return ((const float*)p)[idx];
}
__device__ __forceinline__ void stf(void* p, long idx, float v, bool isb) {
  if (isb) ((bf16*)p)[idx] = __float2bfloat16(v);
  else     ((float*)p)[idx] = v;
}
// butterfly sum across the full 64-lane wave
__device__ __forceinline__ float wsum64(float x) {
#pragma unroll
  for (int off = 32; off > 0; off >>= 1) x += __shfl_xor(x, off, 64);
  return x;
}

// ---------------------------------------------------------------------------
// Kernel 1: per-node pipeline. 256 threads per residue.
// ---------------------------------------------------------------------------
__global__ __launch_bounds__(256) void k_node(
    const void* __restrict__ xyz, const void* __restrict__ state,
    const void* __restrict__ msa, const void* __restrict__ seq1hot,
    const void* __restrict__ g_msa, const void* __restrict__ b_msa,
    const void* __restrict__ g_state, const void* __restrict__ b_state,
    const void* __restrict__ g_node, const void* __restrict__ b_node,
    const void* __restrict__ Wx, const void* __restrict__ bx,
    const void* __restrict__ Wvv,
    float* __restrict__ l0, float* __restrict__ CA, float* __restrict__ v,
    float* __restrict__ vproj, float* __restrict__ agg, float* __restrict__ v_agg)
{
  const bool isb = detect_bf16(g_msa);
  const int i = blockIdx.x;
  const int t = threadIdx.x;
  const int lane = t & 63, w = t >> 6;
  __shared__ float nin[312];
  __shared__ float wred[2][4];
  __shared__ float part[8][32];
  __shared__ float sxyz[9], sv9[9];

  // ---- msa LN (256): one element per thread ----
  float x = ldf(msa, i * 256 + t, isb);
  float s1 = wsum64(x), s2 = wsum64(x * x);
  if (lane == 0) { wred[0][w] = s1; wred[1][w] = s2; }
  if (t < 9) sxyz[t] = ldf(xyz, i * 9 + t, isb);
  __syncthreads();
  float S  = wred[0][0] + wred[0][1] + wred[0][2] + wred[0][3];
  float Sq = wred[1][0] + wred[1][1] + wred[1][2] + wred[1][3];
  float mu = S * (1.f / 256.f);
  float rs = rsqrtf(fmaxf(Sq * (1.f / 256.f) - mu * mu, 0.f) + 1e-5f);
  nin[t] = (x - mu) * rs * ldf(g_msa, t, isb) + ldf(b_msa, t, isb);
  if (t < 21) nin[256 + t] = ldf(seq1hot, i * 21 + t, isb);
  if (t < 3)  nin[309 + t] = 0.f;

  // ---- state LN (32): wave 0 only ----
  if (w == 0) {
    float sx  = (lane < 32) ? ldf(state, i * 32 + lane, isb) : 0.f;
    float Ss  = wsum64(sx), Ssq = wsum64(sx * sx);
    float mus = Ss * (1.f / 32.f);
    float rss = rsqrtf(fmaxf(Ssq * (1.f / 32.f) - mus * mus, 0.f) + 1e-5f);
    if (lane < 32)
      nin[277 + lane] = (sx - mus) * rss * ldf(g_state, lane, isb) + ldf(b_state, lane, isb);
  }
  __syncthreads();

  // ---- Wx GEMV: thread (c, g) handles rows f ≡ g (mod 8) ----
  const int c = t & 31, g = t >> 5;
  float acc = 0.f;
  for (int f = g; f < 309; f += 8) acc += nin[f] * ldf(Wx, f * 32 + c, isb);
  part[g][c] = acc;
  __syncthreads();

  if (w == 0) {
    float a = 0.f;
    if (lane < 32) {
      a = ldf(bx, lane, isb);
#pragma unroll
      for (int gg = 0; gg < 8; ++gg) a += part[gg][lane];
    }
    float Sa = wsum64(a), Saq = wsum64(a * a);   // lanes >=32 contribute 0
    float mn = Sa * (1.f / 32.f);
    float rn = rsqrtf(fmaxf(Saq * (1.f / 32.f) - mn * mn, 0.f) + 1e-5f);
    if (lane < 32)
      l0[i * 32 + lane] = (a - mn) * rn * ldf(g_node, lane, isb) + ldf(b_node, lane, isb);
  } else if (w == 1) {
    if (lane < 3) CA[i * 3 + lane] = sxyz[3 + lane];
    if (lane < 9) {
      float vv = sxyz[lane] - sxyz[3 + lane % 3];
      v[i * 9 + lane] = vv;
      sv9[lane] = vv;
    }
    if (lane < 32) agg[i * 32 + lane] = 0.f;
  } else if (w == 2) {
    if (lane < 9) v_agg[i * 9 + lane] = 0.f;
  }
  __syncthreads();
  if (w == 1 && lane < 9) {
    int o = lane / 3, xc = lane % 3;
    float s = 0.f;
#pragma unroll
    for (int ii = 0; ii < 3; ++ii) s += ldf(Wvv, ii * 3 + o, isb) * sv9[ii * 3 + xc];
    vproj[i * 9 + lane] = s;
  }
}

// ---------------------------------------------------------------------------
// Kernel 2: top-64 NN per residue (bitonic sort of 512 packed keys).
// ---------------------------------------------------------------------------
__global__ __launch_bounds__(256) void k_topk(
    const float* __restrict__ CA, int* __restrict__ nbr)
{
  __shared__ float cx[512], cy[512], cz[512];
  __shared__ unsigned long long key[512];
  const int i = blockIdx.x;
  for (int t = threadIdx.x; t < 512; t += 256) {
    cx[t] = CA[t * 3 + 0];
    cy[t] = CA[t * 3 + 1];
    cz[t] = CA[t * 3 + 2];
  }
  __syncthreads();
  float xi = cx[i], yi = cy[i], zi = cz[i];
  for (int t = threadIdx.x; t < 512; t += 256) {
    float dx = cx[t] - xi, dy = cy[t] - yi, dz = cz[t] - zi;
    float d2 = dx * dx + dy * dy + dz * dz;
    unsigned int bits = (t == i) ? 0x7f800000u : __float_as_uint(d2);  // diag -> +inf
    key[t] = ((unsigned long long)bits << 32) | (unsigned int)t;
  }
  for (int k = 2; k <= 512; k <<= 1) {
    for (int j = k >> 1; j > 0; j >>= 1) {
      __syncthreads();
      int t  = threadIdx.x;
      int i0 = ((t & ~(j - 1)) << 1) | (t & (j - 1));
      int i1 = i0 | j;
      bool up = ((i0 & k) == 0);
      unsigned long long a = key[i0], b = key[i1];
      if ((a > b) == up) { key[i0] = b; key[i1] = a; }
    }
  }
  __syncthreads();
  if (threadIdx.x < 64)
    nbr[i * 64 + threadIdx.x] = (int)(key[threadIdx.x] & 0xffffffffu);
}

// ---------------------------------------------------------------------------
// Kernel 3: per-edge messages + scatter. 1024 blocks: (src i, half); 4 waves,
// one wave per edge, 8 edges per wave. NO in-loop barriers: ped[w]/sinv[w]
// are wave-private LDS scratch (written+read only by wave w; same-wave LDS
// ordering is guaranteed via compiler lgkmcnt).
// ---------------------------------------------------------------------------
__global__ __launch_bounds__(256, 4) void k_edge(
    const void* __restrict__ pair,
    const void* __restrict__ g_pair, const void* __restrict__ b_pair,
    const void* __restrict__ We1, const void* __restrict__ be1,
    const void* __restrict__ g_e1, const void* __restrict__ b_e1,
    const void* __restrict__ W1, const void* __restrict__ b1,
    const void* __restrict__ Wv,
    const int* __restrict__ nbr,
    const float* __restrict__ l0, const float* __restrict__ CA,
    const float* __restrict__ v, const float* __restrict__ vproj,
    float* __restrict__ agg, float* __restrict__ v_agg)
{
  const bool isb = detect_bf16(g_pair);
  __shared__ float sWe1[128 * 32];
  __shared__ float sW1[100 * 32];
  __shared__ float sWv[192];
  __shared__ float sgp[128], sbp[128];
  __shared__ float sbe1[32], sge1[32], sbee[32], sb1[32];
  __shared__ float sl0i[32], sCAi[3], svi[9], svpi[9];
  __shared__ float ped[4][128];
  __shared__ float sinv[4][100];

  const int i    = blockIdx.x >> 1;
  const int half = blockIdx.x & 1;
  const int tid  = threadIdx.x;
  for (int t = tid; t < 128 * 32; t += 256) sWe1[t] = ldf(We1, t, isb);
  for (int t = tid; t < 100 * 32; t += 256) sW1[t]  = ldf(W1, t, isb);
  if (tid < 192) sWv[tid] = ldf(Wv, tid, isb);
  if (tid < 128) { sgp[tid] = ldf(g_pair, tid, isb); sbp[tid] = ldf(b_pair, tid, isb); }
  if (tid >= 128 && tid < 160) {
    int cc = tid - 128;
    sbe1[cc] = ldf(be1, cc, isb); sge1[cc] = ldf(g_e1, cc, isb);
    sbee[cc] = ldf(b_e1, cc, isb); sb1[cc] = ldf(b1, cc, isb);
  }
  if (tid >= 224) sl0i[tid - 224] = l0[i * 32 + (tid - 224)];
  if (tid < 3) sCAi[tid] = CA[i * 3 + tid];
  if (tid >= 64 && tid < 73)  svi[tid - 64]  = v[i * 9 + (tid - 64)];
  if (tid >= 96 && tid < 105) svpi[tid - 96] = vproj[i * 9 + (tid - 96)];
  __syncthreads();   // the ONLY block-wide barrier

  const int w = tid >> 6, lane = tid & 63;
  const int c = lane & 31, h = lane >> 5;

  // constant part of inv (l0[i]) — wave-private slot, written once
  if (h == 0) sinv[w][c] = sl0i[c];

  for (int step = 0; step < 8; ++step) {
    const int kk = half * 32 + step * 4 + w;
    const int j  = nbr[i * 64 + kk];
    const size_t pbase = ((size_t)(i * 512 + j)) * 128;

    // pair row: 2 consecutive elements per lane
    float p0, p1;
    if (isb) {
      p0 = __bfloat162float(((const bf16*)pair)[pbase + 2 * lane]);
      p1 = __bfloat162float(((const bf16*)pair)[pbase + 2 * lane + 1]);
    } else {
      float2 pp = ((const float2*)pair)[(pbase >> 1) + lane];
      p0 = pp.x; p1 = pp.y;
    }
    float lj  = l0[j * 32 + c];                 // all lanes (both halves)
    float cax = CA[j * 3 + 0], cay = CA[j * 3 + 1], caz = CA[j * 3 + 2];

    float S  = wsum64(p0 + p1);
    float Sq = wsum64(p0 * p0 + p1 * p1);
    float mu = S * (1.f / 128.f);
    float rs = rsqrtf(fmaxf(Sq * (1.f / 128.f) - mu * mu, 0.f) + 1e-5f);
    ped[w][2 * lane]     = (p0 - mu) * rs * sgp[2 * lane]     + sbp[2 * lane];
    ped[w][2 * lane + 1] = (p1 - mu) * rs * sgp[2 * lane + 1] + sbp[2 * lane + 1];
    // wave-private: no __syncthreads needed (lgkmcnt orders write->read)

    // e1 = LN(pe @ We1 + be1): lane (c,h), inner half each
    float acc = 0.f;
    {
      const float* pw = ped[w];
      const int fb = h * 64;
#pragma unroll
      for (int f = 0; f < 64; ++f) acc += pw[fb + f] * sWe1[(fb + f) * 32 + c];
    }
    acc += __shfl_xor(acc, 32, 64);
    acc += sbe1[c];
    float m2 = wsum64(acc) * (1.f / 64.f);                       // halves duplicated
    float r2 = rsqrtf(fmaxf(wsum64(acc * acc) * (1.f / 64.f) - m2 * m2, 0.f) + 1e-5f);
    float we = (acc - m2) * r2 * sge1[c] + sbee[c];

    // geometry (all lanes)
    float dex = cax - sCAi[0], dey = cay - sCAi[1], dez = caz - sCAi[2];
    float dn  = sqrtf(dex * dex + dey * dey + dez * dez);
    float idn = 1.f / (dn + 1e-8f);
    float dux = dex * idn, duy = dey * idn, duz = dez * idn;

    if (h == 0) { sinv[w][32 + c] = lj; sinv[w][64 + c] = we; }
    if (lane == 0) {
      sinv[w][96] = dn;
      sinv[w][97] = svi[0] * dux + svi[1] * duy + svi[2] * duz;
      sinv[w][98] = svi[3] * dux + svi[4] * duy + svi[5] * duz;
      sinv[w][99] = svi[6] * dux + svi[7] * duy + svi[8] * duz;
    }
    // wave-private: no __syncthreads needed

    // m = gelu(inv @ W1 + b1)
    float a1 = 0.f;
    {
      const float* iv = sinv[w];
      const int fb = h * 50;
#pragma unroll
      for (int f = 0; f < 50; ++f) a1 += iv[fb + f] * sW1[(fb + f) * 32 + c];
    }
    a1 += __shfl_xor(a1, 32, 64);
    a1 += sb1[c];
    float u  = 0.7978845608028654f * (a1 + 0.044715f * a1 * a1 * a1);
    float mm = 0.5f * a1 * (1.f + tanhf(u));   // jax.nn.gelu approximate=True

    if (h == 0) atomicAdd(&agg[j * 32 + c], mm);

    // coef = m @ Wv (6 butterfly sums; halves duplicated -> x0.5)
    float co[6];
#pragma unroll
    for (int o = 0; o < 6; ++o) co[o] = 0.5f * wsum64(mm * sWv[c * 6 + o]);
    if (lane < 9) {
      int o = lane / 3, xx = lane % 3;
      float dcomp = (xx == 0) ? dex : ((xx == 1) ? dey : dez);
      atomicAdd(&v_agg[j * 9 + lane], co[o] * dcomp + co[3 + o] * svpi[o * 3 + xx]);
    }
  }
}

// ---------------------------------------------------------------------------
// Kernel 4: output heads. grid 512, block 64.
// ---------------------------------------------------------------------------
__global__ __launch_bounds__(64) void k_out(
    const float* __restrict__ l0, const float* __restrict__ agg,
    const float* __restrict__ v, const float* __restrict__ v_agg,
    const float* __restrict__ CA,
    const void* __restrict__ W2, const void* __restrict__ b2,
    const void* __restrict__ Wself,
    const void* __restrict__ g_state, const void* __restrict__ b_state,
    const void* __restrict__ Wl, const void* __restrict__ bl,
    void* __restrict__ out)
{
  const bool isb = detect_bf16(g_state);
  const int l = blockIdx.x;
  const int lane = threadIdx.x;
  const int c = lane & 31, h = lane >> 5;
  __shared__ float scat[64], soff[9];
  if (lane < 32) { scat[lane] = l0[l * 32 + lane]; scat[32 + lane] = agg[l * 32 + lane]; }
  __syncthreads();

  // h_out = [l0, agg] @ W2 + b2 : lane (c,h), inner half each
  float acc = 0.f;
  {
    const int fb = h * 32;
    for (int f = 0; f < 32; ++f) acc += scat[fb + f] * ldf(W2, (fb + f) * 32 + c, isb);
  }
  acc += __shfl_xor(acc, 32, 64);
  acc += ldf(b2, c, isb);

  float mu = wsum64(acc) * (1.f / 64.f);
  float rs = rsqrtf(fmaxf(wsum64(acc * acc) * (1.f / 64.f) - mu * mu, 0.f) + 1e-5f);
  float hn = (acc - mu) * rs * ldf(g_state, c, isb) + ldf(b_state, c, isb);
  float pre = 0.5f * wsum64(hn * ldf(Wl, c, isb)) + ldf(bl, 0, isb);
  if (lane == 0) stf(out, 4608 + l, 1.f / (1.f + expf(-pre)), isb);

  if (lane < 9) {
    int o = lane / 3, xx = lane % 3;
    float s = v_agg[l * 9 + lane];
#pragma unroll
    for (int ii = 0; ii < 3; ++ii) s += ldf(Wself, ii * 3 + o, isb) * v[l * 9 + ii * 3 + xx];
    soff[lane] = s;
  }
  __syncthreads();
  if (lane < 9) {
    int xx = lane % 3;
    float add = (l == 0) ? 0.f : (CA[l * 3 + xx] + soff[3 + xx]);  // residue 0 zeroed
    stf(out, l * 9 + lane, soff[lane] + add, isb);
  }
}

extern "C" void kernel_launch(void* const* d_in, const int* in_sizes, int n_in,
                              void* d_out, int out_size, void* d_ws, size_t ws_size,
                              hipStream_t stream) {
  (void)in_sizes; (void)n_in; (void)out_size; (void)ws_size;
  const void* xyz     = d_in[0];
  const void* state   = d_in[1];
  const void* msa     = d_in[4];
  const void* pair    = d_in[5];
  const void* seq1hot = d_in[6];
  const void* g_msa   = d_in[10];
  const void* b_msa   = d_in[11];
  const void* g_pair  = d_in[12];
  const void* b_pair  = d_in[13];
  const void* g_state = d_in[14];
  const void* b_state = d_in[15];
  const void* g_node  = d_in[16];
  const void* b_node  = d_in[17];
  const void* g_e1    = d_in[18];
  const void* b_e1    = d_in[19];
  const void* Wx      = d_in[20];
  const void* bx      = d_in[21];
  const void* We1     = d_in[22];
  const void* be1     = d_in[23];
  const void* W1      = d_in[24];
  const void* b1      = d_in[25];
  const void* W2      = d_in[26];
  const void* b2      = d_in[27];
  const void* Wv      = d_in[28];
  const void* Wvv     = d_in[29];
  const void* Wself   = d_in[30];
  const void* Wl      = d_in[31];
  const void* bl      = d_in[32];

  float* ws    = (float*)d_ws;
  float* l0    = ws;            // 512*32
  float* CA    = ws + 16384;    // 512*3
  float* v     = ws + 17920;    // 512*9
  float* vproj = ws + 22528;    // 512*9
  float* agg   = ws + 27136;    // 512*32
  float* v_agg = ws + 43520;    // 512*9
  int*   nbr   = (int*)(ws + 48128);  // 512*64 ints

  hipLaunchKernelGGL(k_node, dim3(512), dim3(256), 0, stream,
                     xyz, state, msa, seq1hot, g_msa, b_msa, g_state, b_state,
                     g_node, b_node, Wx, bx, Wvv, l0, CA, v, vproj, agg, v_agg);
  hipLaunchKernelGGL(k_topk, dim3(512), dim3(256), 0, stream, CA, nbr);
  hipLaunchKernelGGL(k_edge, dim3(1024), dim3(256), 0, stream,
                     pair, g_pair, b_pair, We1, be1, g_e1, b_e1, W1, b1, Wv,
                     nbr, l0, CA, v, vproj, agg, v_agg);
  hipLaunchKernelGGL(k_out, dim3(512), dim3(64), 0, stream,
                     l0, agg, v, v_agg, CA, W2, b2, Wself, g_state, b_state, Wl, bl,
                     (void*)d_out);
}

// Round 6
// 325.029 us; speedup vs baseline: 1.2118x; 1.2118x over previous
//
#include <hip/hip_runtime.h>
#include <hip/hip_bf16.h>
#include <math.h>

typedef __hip_bfloat16 bf16;

// dtype: inputs are f32 (measured round 3), but keep runtime detect via the
// first 32-bit word of a ones-vector: f32 -> 0x3F800000, bf16 -> 0x3F803F80.
__device__ __forceinline__ bool detect_bf16(const void* ones_vec) {
  return ((const unsigned int*)ones_vec)[0] == 0x3F803F80u;
}
__device__ __forceinline__ float ldf(const void* p, long idx, bool isb) {
  if (isb) return __bfloat162float(((const bf16*)p)[idx]);
  return ((const float*)p)[idx];
}
__device__ __forceinline__ void stf(void* p, long idx, float v, bool isb) {
  if (isb) ((bf16*)p)[idx] = __float2bfloat16(v);
  else     ((float*)p)[idx] = v;
}
// butterfly sum across the full 64-lane wave
__device__ __forceinline__ float wsum64(float x) {
#pragma unroll
  for (int off = 32; off > 0; off >>= 1) x += __shfl_xor(x, off, 64);
  return x;
}

// ---------------------------------------------------------------------------
// Kernel 1: per-node pipeline. 256 threads per residue.
// ---------------------------------------------------------------------------
__global__ __launch_bounds__(256) void k_node(
    const void* __restrict__ xyz, const void* __restrict__ state,
    const void* __restrict__ msa, const void* __restrict__ seq1hot,
    const void* __restrict__ g_msa, const void* __restrict__ b_msa,
    const void* __restrict__ g_state, const void* __restrict__ b_state,
    const void* __restrict__ g_node, const void* __restrict__ b_node,
    const void* __restrict__ Wx, const void* __restrict__ bx,
    const void* __restrict__ Wvv,
    float* __restrict__ l0, float* __restrict__ CA, float* __restrict__ v,
    float* __restrict__ vproj, float* __restrict__ agg, float* __restrict__ v_agg)
{
  const bool isb = detect_bf16(g_msa);
  const int i = blockIdx.x;
  const int t = threadIdx.x;
  const int lane = t & 63, w = t >> 6;
  __shared__ float nin[312];
  __shared__ float wred[2][4];
  __shared__ float part[8][32];
  __shared__ float sxyz[9], sv9[9];

  // ---- msa LN (256): one element per thread ----
  float x = ldf(msa, i * 256 + t, isb);
  float s1 = wsum64(x), s2 = wsum64(x * x);
  if (lane == 0) { wred[0][w] = s1; wred[1][w] = s2; }
  if (t < 9) sxyz[t] = ldf(xyz, i * 9 + t, isb);
  __syncthreads();
  float S  = wred[0][0] + wred[0][1] + wred[0][2] + wred[0][3];
  float Sq = wred[1][0] + wred[1][1] + wred[1][2] + wred[1][3];
  float mu = S * (1.f / 256.f);
  float rs = rsqrtf(fmaxf(Sq * (1.f / 256.f) - mu * mu, 0.f) + 1e-5f);
  nin[t] = (x - mu) * rs * ldf(g_msa, t, isb) + ldf(b_msa, t, isb);
  if (t < 21) nin[256 + t] = ldf(seq1hot, i * 21 + t, isb);
  if (t < 3)  nin[309 + t] = 0.f;

  // ---- state LN (32): wave 0 only ----
  if (w == 0) {
    float sx  = (lane < 32) ? ldf(state, i * 32 + lane, isb) : 0.f;
    float Ss  = wsum64(sx), Ssq = wsum64(sx * sx);
    float mus = Ss * (1.f / 32.f);
    float rss = rsqrtf(fmaxf(Ssq * (1.f / 32.f) - mus * mus, 0.f) + 1e-5f);
    if (lane < 32)
      nin[277 + lane] = (sx - mus) * rss * ldf(g_state, lane, isb) + ldf(b_state, lane, isb);
  }
  __syncthreads();

  // ---- Wx GEMV: thread (c, g) handles rows f ≡ g (mod 8) ----
  const int c = t & 31, g = t >> 5;
  float acc = 0.f;
  for (int f = g; f < 309; f += 8) acc += nin[f] * ldf(Wx, f * 32 + c, isb);
  part[g][c] = acc;
  __syncthreads();

  if (w == 0) {
    float a = 0.f;
    if (lane < 32) {
      a = ldf(bx, lane, isb);
#pragma unroll
      for (int gg = 0; gg < 8; ++gg) a += part[gg][lane];
    }
    float Sa = wsum64(a), Saq = wsum64(a * a);   // lanes >=32 contribute 0
    float mn = Sa * (1.f / 32.f);
    float rn = rsqrtf(fmaxf(Saq * (1.f / 32.f) - mn * mn, 0.f) + 1e-5f);
    if (lane < 32)
      l0[i * 32 + lane] = (a - mn) * rn * ldf(g_node, lane, isb) + ldf(b_node, lane, isb);
  } else if (w == 1) {
    if (lane < 3) CA[i * 3 + lane] = sxyz[3 + lane];
    if (lane < 9) {
      float vv = sxyz[lane] - sxyz[3 + lane % 3];
      v[i * 9 + lane] = vv;
      sv9[lane] = vv;
    }
    if (lane < 32) agg[i * 32 + lane] = 0.f;
  } else if (w == 2) {
    if (lane < 9) v_agg[i * 9 + lane] = 0.f;
  }
  __syncthreads();
  if (w == 1 && lane < 9) {
    int o = lane / 3, xc = lane % 3;
    float s = 0.f;
#pragma unroll
    for (int ii = 0; ii < 3; ++ii) s += ldf(Wvv, ii * 3 + o, isb) * sv9[ii * 3 + xc];
    vproj[i * 9 + lane] = s;
  }
}

// ---------------------------------------------------------------------------
// Kernel 2: top-64 NN per residue (bitonic sort of 512 packed keys).
// ---------------------------------------------------------------------------
__global__ __launch_bounds__(256) void k_topk(
    const float* __restrict__ CA, int* __restrict__ nbr)
{
  __shared__ float cx[512], cy[512], cz[512];
  __shared__ unsigned long long key[512];
  const int i = blockIdx.x;
  for (int t = threadIdx.x; t < 512; t += 256) {
    cx[t] = CA[t * 3 + 0];
    cy[t] = CA[t * 3 + 1];
    cz[t] = CA[t * 3 + 2];
  }
  __syncthreads();
  float xi = cx[i], yi = cy[i], zi = cz[i];
  for (int t = threadIdx.x; t < 512; t += 256) {
    float dx = cx[t] - xi, dy = cy[t] - yi, dz = cz[t] - zi;
    float d2 = dx * dx + dy * dy + dz * dz;
    unsigned int bits = (t == i) ? 0x7f800000u : __float_as_uint(d2);  // diag -> +inf
    key[t] = ((unsigned long long)bits << 32) | (unsigned int)t;
  }
  for (int k = 2; k <= 512; k <<= 1) {
    for (int j = k >> 1; j > 0; j >>= 1) {
      __syncthreads();
      int t  = threadIdx.x;
      int i0 = ((t & ~(j - 1)) << 1) | (t & (j - 1));
      int i1 = i0 | j;
      bool up = ((i0 & k) == 0);
      unsigned long long a = key[i0], b = key[i1];
      if ((a > b) == up) { key[i0] = b; key[i1] = a; }
    }
  }
  __syncthreads();
  if (threadIdx.x < 64)
    nbr[i * 64 + threadIdx.x] = (int)(key[threadIdx.x] & 0xffffffffu);
}

// ---------------------------------------------------------------------------
// Kernel 3: per-edge messages + scatter. 1024 blocks: (src i, half); 4 waves,
// one wave per edge, 8 edges per wave. Two in-loop barriers per step —
// KEEP THEM: removing them (round 5) made the compiler unroll/pipeline all 8
// steps, spill to scratch, and blow FETCH_SIZE from 9 MB to 211 MB.
// ---------------------------------------------------------------------------
__global__ __launch_bounds__(256) void k_edge(
    const void* __restrict__ pair,
    const void* __restrict__ g_pair, const void* __restrict__ b_pair,
    const void* __restrict__ We1, const void* __restrict__ be1,
    const void* __restrict__ g_e1, const void* __restrict__ b_e1,
    const void* __restrict__ W1, const void* __restrict__ b1,
    const void* __restrict__ Wv,
    const int* __restrict__ nbr,
    const float* __restrict__ l0, const float* __restrict__ CA,
    const float* __restrict__ v, const float* __restrict__ vproj,
    float* __restrict__ agg, float* __restrict__ v_agg)
{
  const bool isb = detect_bf16(g_pair);
  __shared__ float sWe1[128 * 32];
  __shared__ float sW1[100 * 32];
  __shared__ float sWv[192];
  __shared__ float sgp[128], sbp[128];
  __shared__ float sbe1[32], sge1[32], sbee[32], sb1[32];
  __shared__ float sl0i[32], sCAi[3], svi[9], svpi[9];
  __shared__ float ped[4][128];
  __shared__ float sinv[4][100];

  const int i    = blockIdx.x >> 1;
  const int half = blockIdx.x & 1;
  const int tid  = threadIdx.x;
  for (int t = tid; t < 128 * 32; t += 256) sWe1[t] = ldf(We1, t, isb);
  for (int t = tid; t < 100 * 32; t += 256) sW1[t]  = ldf(W1, t, isb);
  if (tid < 192) sWv[tid] = ldf(Wv, tid, isb);
  if (tid < 128) { sgp[tid] = ldf(g_pair, tid, isb); sbp[tid] = ldf(b_pair, tid, isb); }
  if (tid >= 128 && tid < 160) {
    int cc = tid - 128;
    sbe1[cc] = ldf(be1, cc, isb); sge1[cc] = ldf(g_e1, cc, isb);
    sbee[cc] = ldf(b_e1, cc, isb); sb1[cc] = ldf(b1, cc, isb);
  }
  if (tid >= 224) sl0i[tid - 224] = l0[i * 32 + (tid - 224)];
  if (tid < 3) sCAi[tid] = CA[i * 3 + tid];
  if (tid >= 64 && tid < 73)  svi[tid - 64]  = v[i * 9 + (tid - 64)];
  if (tid >= 96 && tid < 105) svpi[tid - 96] = vproj[i * 9 + (tid - 96)];
  __syncthreads();

  const int w = tid >> 6, lane = tid & 63;
  const int c = lane & 31, h = lane >> 5;

  // constant part of inv (l0[i]) — written once, read after >=2 barriers
  if (h == 0) sinv[w][c] = sl0i[c];

  for (int step = 0; step < 8; ++step) {
    const int kk = half * 32 + step * 4 + w;
    const int j  = nbr[i * 64 + kk];
    const size_t pbase = ((size_t)(i * 512 + j)) * 128;

    // pair row: 2 consecutive elements per lane
    float p0, p1;
    if (isb) {
      p0 = __bfloat162float(((const bf16*)pair)[pbase + 2 * lane]);
      p1 = __bfloat162float(((const bf16*)pair)[pbase + 2 * lane + 1]);
    } else {
      float2 pp = ((const float2*)pair)[(pbase >> 1) + lane];
      p0 = pp.x; p1 = pp.y;
    }
    float lj = 0.f;
    if (h == 0) lj = l0[j * 32 + c];
    float cax = CA[j * 3 + 0], cay = CA[j * 3 + 1], caz = CA[j * 3 + 2];

    float S  = wsum64(p0 + p1);
    float Sq = wsum64(p0 * p0 + p1 * p1);
    float mu = S * (1.f / 128.f);
    float rs = rsqrtf(fmaxf(Sq * (1.f / 128.f) - mu * mu, 0.f) + 1e-5f);
    ped[w][2 * lane]     = (p0 - mu) * rs * sgp[2 * lane]     + sbp[2 * lane];
    ped[w][2 * lane + 1] = (p1 - mu) * rs * sgp[2 * lane + 1] + sbp[2 * lane + 1];
    __syncthreads();  // S1: ped ready (also a scheduling fence vs. spills)

    // e1 = LN(pe @ We1 + be1): lane (c,h), inner half each
    float acc = 0.f;
    {
      const float* pw = ped[w];
      const int fb = h * 64;
#pragma unroll 8
      for (int f = 0; f < 64; ++f) acc += pw[fb + f] * sWe1[(fb + f) * 32 + c];
    }
    acc += __shfl_xor(acc, 32, 64);
    acc += sbe1[c];
    float m2 = wsum64(acc) * (1.f / 64.f);                       // halves duplicated
    float r2 = rsqrtf(fmaxf(wsum64(acc * acc) * (1.f / 64.f) - m2 * m2, 0.f) + 1e-5f);
    float we = (acc - m2) * r2 * sge1[c] + sbee[c];

    // geometry (all lanes)
    float dex = cax - sCAi[0], dey = cay - sCAi[1], dez = caz - sCAi[2];
    float dn  = sqrtf(dex * dex + dey * dey + dez * dez);
    float idn = 1.f / (dn + 1e-8f);
    float dux = dex * idn, duy = dey * idn, duz = dez * idn;

    if (h == 0) { sinv[w][32 + c] = lj; sinv[w][64 + c] = we; }
    if (lane == 0) {
      sinv[w][96] = dn;
      sinv[w][97] = svi[0] * dux + svi[1] * duy + svi[2] * duz;
      sinv[w][98] = svi[3] * dux + svi[4] * duy + svi[5] * duz;
      sinv[w][99] = svi[6] * dux + svi[7] * duy + svi[8] * duz;
    }
    __syncthreads();  // S2: sinv ready

    // m = gelu(inv @ W1 + b1)
    float a1 = 0.f;
    {
      const float* iv = sinv[w];
      const int fb = h * 50;
#pragma unroll 5
      for (int f = 0; f < 50; ++f) a1 += iv[fb + f] * sW1[(fb + f) * 32 + c];
    }
    a1 += __shfl_xor(a1, 32, 64);
    a1 += sb1[c];
    float u  = 0.7978845608028654f * (a1 + 0.044715f * a1 * a1 * a1);
    float mm = 0.5f * a1 * (1.f + tanhf(u));   // jax.nn.gelu approximate=True

    if (h == 0) atomicAdd(&agg[j * 32 + c], mm);

    // coef = m @ Wv (6 butterfly sums; halves duplicated -> x0.5)
    float co[6];
#pragma unroll
    for (int o = 0; o < 6; ++o) co[o] = 0.5f * wsum64(mm * sWv[c * 6 + o]);
    if (lane < 9) {
      int o = lane / 3, xx = lane % 3;
      float dcomp = (xx == 0) ? dex : ((xx == 1) ? dey : dez);
      atomicAdd(&v_agg[j * 9 + lane], co[o] * dcomp + co[3 + o] * svpi[o * 3 + xx]);
    }
  }
}

// ---------------------------------------------------------------------------
// Kernel 4: output heads. grid 512, block 64.
// ---------------------------------------------------------------------------
__global__ __launch_bounds__(64) void k_out(
    const float* __restrict__ l0, const float* __restrict__ agg,
    const float* __restrict__ v, const float* __restrict__ v_agg,
    const float* __restrict__ CA,
    const void* __restrict__ W2, const void* __restrict__ b2,
    const void* __restrict__ Wself,
    const void* __restrict__ g_state, const void* __restrict__ b_state,
    const void* __restrict__ Wl, const void* __restrict__ bl,
    void* __restrict__ out)
{
  const bool isb = detect_bf16(g_state);
  const int l = blockIdx.x;
  const int lane = threadIdx.x;
  const int c = lane & 31, h = lane >> 5;
  __shared__ float scat[64], soff[9];
  if (lane < 32) { scat[lane] = l0[l * 32 + lane]; scat[32 + lane] = agg[l * 32 + lane]; }
  __syncthreads();

  // h_out = [l0, agg] @ W2 + b2 : lane (c,h), inner half each
  float acc = 0.f;
  {
    const int fb = h * 32;
    for (int f = 0; f < 32; ++f) acc += scat[fb + f] * ldf(W2, (fb + f) * 32 + c, isb);
  }
  acc += __shfl_xor(acc, 32, 64);
  acc += ldf(b2, c, isb);

  float mu = wsum64(acc) * (1.f / 64.f);
  float rs = rsqrtf(fmaxf(wsum64(acc * acc) * (1.f / 64.f) - mu * mu, 0.f) + 1e-5f);
  float hn = (acc - mu) * rs * ldf(g_state, c, isb) + ldf(b_state, c, isb);
  float pre = 0.5f * wsum64(hn * ldf(Wl, c, isb)) + ldf(bl, 0, isb);
  if (lane == 0) stf(out, 4608 + l, 1.f / (1.f + expf(-pre)), isb);

  if (lane < 9) {
    int o = lane / 3, xx = lane % 3;
    float s = v_agg[l * 9 + lane];
#pragma unroll
    for (int ii = 0; ii < 3; ++ii) s += ldf(Wself, ii * 3 + o, isb) * v[l * 9 + ii * 3 + xx];
    soff[lane] = s;
  }
  __syncthreads();
  if (lane < 9) {
    int xx = lane % 3;
    float add = (l == 0) ? 0.f : (CA[l * 3 + xx] + soff[3 + xx]);  // residue 0 zeroed
    stf(out, l * 9 + lane, soff[lane] + add, isb);
  }
}

extern "C" void kernel_launch(void* const* d_in, const int* in_sizes, int n_in,
                              void* d_out, int out_size, void* d_ws, size_t ws_size,
                              hipStream_t stream) {
  (void)in_sizes; (void)n_in; (void)out_size; (void)ws_size;
  const void* xyz     = d_in[0];
  const void* state   = d_in[1];
  const void* msa     = d_in[4];
  const void* pair    = d_in[5];
  const void* seq1hot = d_in[6];
  const void* g_msa   = d_in[10];
  const void* b_msa   = d_in[11];
  const void* g_pair  = d_in[12];
  const void* b_pair  = d_in[13];
  const void* g_state = d_in[14];
  const void* b_state = d_in[15];
  const void* g_node  = d_in[16];
  const void* b_node  = d_in[17];
  const void* g_e1    = d_in[18];
  const void* b_e1    = d_in[19];
  const void* Wx      = d_in[20];
  const void* bx      = d_in[21];
  const void* We1     = d_in[22];
  const void* be1     = d_in[23];
  const void* W1      = d_in[24];
  const void* b1      = d_in[25];
  const void* W2      = d_in[26];
  const void* b2      = d_in[27];
  const void* Wv      = d_in[28];
  const void* Wvv     = d_in[29];
  const void* Wself   = d_in[30];
  const void* Wl      = d_in[31];
  const void* bl      = d_in[32];

  float* ws    = (float*)d_ws;
  float* l0    = ws;            // 512*32
  float* CA    = ws + 16384;    // 512*3
  float* v     = ws + 17920;    // 512*9
  float* vproj = ws + 22528;    // 512*9
  float* agg   = ws + 27136;    // 512*32
  float* v_agg = ws + 43520;    // 512*9
  int*   nbr   = (int*)(ws + 48128);  // 512*64 ints

  hipLaunchKernelGGL(k_node, dim3(512), dim3(256), 0, stream,
                     xyz, state, msa, seq1hot, g_msa, b_msa, g_state, b_state,
                     g_node, b_node, Wx, bx, Wvv, l0, CA, v, vproj, agg, v_agg);
  hipLaunchKernelGGL(k_topk, dim3(512), dim3(256), 0, stream, CA, nbr);
  hipLaunchKernelGGL(k_edge, dim3(1024), dim3(256), 0, stream,
                     pair, g_pair, b_pair, We1, be1, g_e1, b_e1, W1, b1, Wv,
                     nbr, l0, CA, v, vproj, agg, v_agg);
  hipLaunchKernelGGL(k_out, dim3(512), dim3(64), 0, stream,
                     l0, agg, v, v_agg, CA, W2, b2, Wself, g_state, b_state, Wl, bl,
                     (void*)d_out);
}

// Round 7
// 309.145 us; speedup vs baseline: 1.2741x; 1.0514x over previous
//
#include <hip/hip_runtime.h>
#include <hip/hip_bf16.h>
#include <math.h>

typedef __hip_bfloat16 bf16;

// dtype: inputs are f32 (measured round 3), but keep runtime detect via the
// first 32-bit word of a ones-vector: f32 -> 0x3F800000, bf16 -> 0x3F803F80.
__device__ __forceinline__ bool detect_bf16(const void* ones_vec) {
  return ((const unsigned int*)ones_vec)[0] == 0x3F803F80u;
}
__device__ __forceinline__ float ldf(const void* p, long idx, bool isb) {
  if (isb) return __bfloat162float(((const bf16*)p)[idx]);
  return ((const float*)p)[idx];
}
__device__ __forceinline__ void stf(void* p, long idx, float v, bool isb) {
  if (isb) ((bf16*)p)[idx] = __float2bfloat16(v);
  else     ((float*)p)[idx] = v;
}
// butterfly sum across the full 64-lane wave
__device__ __forceinline__ float wsum64(float x) {
#pragma unroll
  for (int off = 32; off > 0; off >>= 1) x += __shfl_xor(x, off, 64);
  return x;
}

// ---------------------------------------------------------------------------
// Kernel 1: per-node pipeline. 256 threads per residue. (unchanged from r6)
// ---------------------------------------------------------------------------
__global__ __launch_bounds__(256) void k_node(
    const void* __restrict__ xyz, const void* __restrict__ state,
    const void* __restrict__ msa, const void* __restrict__ seq1hot,
    const void* __restrict__ g_msa, const void* __restrict__ b_msa,
    const void* __restrict__ g_state, const void* __restrict__ b_state,
    const void* __restrict__ g_node, const void* __restrict__ b_node,
    const void* __restrict__ Wx, const void* __restrict__ bx,
    const void* __restrict__ Wvv,
    float* __restrict__ l0, float* __restrict__ CA, float* __restrict__ v,
    float* __restrict__ vproj, float* __restrict__ agg, float* __restrict__ v_agg)
{
  const bool isb = detect_bf16(g_msa);
  const int i = blockIdx.x;
  const int t = threadIdx.x;
  const int lane = t & 63, w = t >> 6;
  __shared__ float nin[312];
  __shared__ float wred[2][4];
  __shared__ float part[8][32];
  __shared__ float sxyz[9], sv9[9];

  // ---- msa LN (256): one element per thread ----
  float x = ldf(msa, i * 256 + t, isb);
  float s1 = wsum64(x), s2 = wsum64(x * x);
  if (lane == 0) { wred[0][w] = s1; wred[1][w] = s2; }
  if (t < 9) sxyz[t] = ldf(xyz, i * 9 + t, isb);
  __syncthreads();
  float S  = wred[0][0] + wred[0][1] + wred[0][2] + wred[0][3];
  float Sq = wred[1][0] + wred[1][1] + wred[1][2] + wred[1][3];
  float mu = S * (1.f / 256.f);
  float rs = rsqrtf(fmaxf(Sq * (1.f / 256.f) - mu * mu, 0.f) + 1e-5f);
  nin[t] = (x - mu) * rs * ldf(g_msa, t, isb) + ldf(b_msa, t, isb);
  if (t < 21) nin[256 + t] = ldf(seq1hot, i * 21 + t, isb);
  if (t < 3)  nin[309 + t] = 0.f;

  // ---- state LN (32): wave 0 only ----
  if (w == 0) {
    float sx  = (lane < 32) ? ldf(state, i * 32 + lane, isb) : 0.f;
    float Ss  = wsum64(sx), Ssq = wsum64(sx * sx);
    float mus = Ss * (1.f / 32.f);
    float rss = rsqrtf(fmaxf(Ssq * (1.f / 32.f) - mus * mus, 0.f) + 1e-5f);
    if (lane < 32)
      nin[277 + lane] = (sx - mus) * rss * ldf(g_state, lane, isb) + ldf(b_state, lane, isb);
  }
  __syncthreads();

  // ---- Wx GEMV: thread (c, g) handles rows f ≡ g (mod 8) ----
  const int c = t & 31, g = t >> 5;
  float acc = 0.f;
  for (int f = g; f < 309; f += 8) acc += nin[f] * ldf(Wx, f * 32 + c, isb);
  part[g][c] = acc;
  __syncthreads();

  if (w == 0) {
    float a = 0.f;
    if (lane < 32) {
      a = ldf(bx, lane, isb);
#pragma unroll
      for (int gg = 0; gg < 8; ++gg) a += part[gg][lane];
    }
    float Sa = wsum64(a), Saq = wsum64(a * a);   // lanes >=32 contribute 0
    float mn = Sa * (1.f / 32.f);
    float rn = rsqrtf(fmaxf(Saq * (1.f / 32.f) - mn * mn, 0.f) + 1e-5f);
    if (lane < 32)
      l0[i * 32 + lane] = (a - mn) * rn * ldf(g_node, lane, isb) + ldf(b_node, lane, isb);
  } else if (w == 1) {
    if (lane < 3) CA[i * 3 + lane] = sxyz[3 + lane];
    if (lane < 9) {
      float vv = sxyz[lane] - sxyz[3 + lane % 3];
      v[i * 9 + lane] = vv;
      sv9[lane] = vv;
    }
    if (lane < 32) agg[i * 32 + lane] = 0.f;
  } else if (w == 2) {
    if (lane < 9) v_agg[i * 9 + lane] = 0.f;
  }
  __syncthreads();
  if (w == 1 && lane < 9) {
    int o = lane / 3, xc = lane % 3;
    float s = 0.f;
#pragma unroll
    for (int ii = 0; ii < 3; ++ii) s += ldf(Wvv, ii * 3 + o, isb) * sv9[ii * 3 + xc];
    vproj[i * 9 + lane] = s;
  }
}

// ---------------------------------------------------------------------------
// Kernel 2: top-64 NN per residue (bitonic sort of 512 packed keys). unchanged
// ---------------------------------------------------------------------------
__global__ __launch_bounds__(256) void k_topk(
    const float* __restrict__ CA, int* __restrict__ nbr)
{
  __shared__ float cx[512], cy[512], cz[512];
  __shared__ unsigned long long key[512];
  const int i = blockIdx.x;
  for (int t = threadIdx.x; t < 512; t += 256) {
    cx[t] = CA[t * 3 + 0];
    cy[t] = CA[t * 3 + 1];
    cz[t] = CA[t * 3 + 2];
  }
  __syncthreads();
  float xi = cx[i], yi = cy[i], zi = cz[i];
  for (int t = threadIdx.x; t < 512; t += 256) {
    float dx = cx[t] - xi, dy = cy[t] - yi, dz = cz[t] - zi;
    float d2 = dx * dx + dy * dy + dz * dz;
    unsigned int bits = (t == i) ? 0x7f800000u : __float_as_uint(d2);  // diag -> +inf
    key[t] = ((unsigned long long)bits << 32) | (unsigned int)t;
  }
  for (int k = 2; k <= 512; k <<= 1) {
    for (int j = k >> 1; j > 0; j >>= 1) {
      __syncthreads();
      int t  = threadIdx.x;
      int i0 = ((t & ~(j - 1)) << 1) | (t & (j - 1));
      int i1 = i0 | j;
      bool up = ((i0 & k) == 0);
      unsigned long long a = key[i0], b = key[i1];
      if ((a > b) == up) { key[i0] = b; key[i1] = a; }
    }
  }
  __syncthreads();
  if (threadIdx.x < 64)
    nbr[i * 64 + threadIdx.x] = (int)(key[threadIdx.x] & 0xffffffffu);
}

// ---------------------------------------------------------------------------
// Kernel 3 (v3): per-edge messages + scatter. 1024 blocks (i, half), 4 waves,
// 8 edges/wave. Weights live in REGISTERS (loop-invariant per lane): lane
// (c,h) holds We1 col c rows h*64..+63 (64 regs) and W1 col c rows h*52..+51
// (52 regs, zero-padded past 100). Edge vectors ped/sinv are wave-private LDS
// read as broadcast float4. No in-loop barriers (r5 proved wave-private LDS
// correctness); `#pragma unroll 1` prevents the r5 cross-step spill explosion.
// Next edge's pair row / l0 / CA are software-prefetched.
// ---------------------------------------------------------------------------
__global__ __launch_bounds__(256) void k_edge(
    const void* __restrict__ pair,
    const void* __restrict__ g_pair, const void* __restrict__ b_pair,
    const void* __restrict__ We1, const void* __restrict__ be1,
    const void* __restrict__ g_e1, const void* __restrict__ b_e1,
    const void* __restrict__ W1, const void* __restrict__ b1,
    const void* __restrict__ Wv,
    const int* __restrict__ nbr,
    const float* __restrict__ l0, const float* __restrict__ CA,
    const float* __restrict__ v, const float* __restrict__ vproj,
    float* __restrict__ agg, float* __restrict__ v_agg)
{
  const bool isb = detect_bf16(g_pair);
  __shared__ float ped[4][128];
  __shared__ float sinv[4][104];
  __shared__ float sgeo[21];   // CAi[3], vi[9], vpi[9]

  const int i    = blockIdx.x >> 1;
  const int half = blockIdx.x & 1;
  const int tid  = threadIdx.x;
  const int w = tid >> 6, lane = tid & 63;
  const int c = lane & 31, h = lane >> 5;

  if (tid < 3)  sgeo[tid] = CA[i * 3 + tid];
  else if (tid < 12) sgeo[tid] = v[i * 9 + (tid - 3)];
  else if (tid < 21) sgeo[tid] = vproj[i * 9 + (tid - 12)];

  // ---- loop-invariant per-lane registers ----
  // We1 column c, rows h*64..h*64+63  (coalesced: 32 consecutive dwords/half)
  float we1r[64];
#pragma unroll
  for (int t = 0; t < 64; ++t) we1r[t] = ldf(We1, (h * 64 + t) * 32 + c, isb);
  // W1 column c, rows h*52..h*52+51, zero past row 100
  float w1r[52];
#pragma unroll
  for (int t = 0; t < 52; ++t) {
    int f = h * 52 + t;
    w1r[t] = (f < 100) ? ldf(W1, f * 32 + c, isb) : 0.f;
  }
  // pair-LN params for this lane's two elements
  const float gp0 = ldf(g_pair, 2 * lane, isb),     gp1 = ldf(g_pair, 2 * lane + 1, isb);
  const float bp0 = ldf(b_pair, 2 * lane, isb),     bp1 = ldf(b_pair, 2 * lane + 1, isb);
  const float be1c = ldf(be1, c, isb), ge1c = ldf(g_e1, c, isb);
  const float bee1c = ldf(b_e1, c, isb), b1c = ldf(b1, c, isb);
  float wvr[6];
#pragma unroll
  for (int o = 0; o < 6; ++o) wvr[o] = ldf(Wv, c * 6 + o, isb);

  // constant + padded parts of inv (wave-private slots, written once)
  if (h == 0) {
    sinv[w][c] = l0[i * 32 + c];
    if (c < 4) sinv[w][100 + c] = 0.f;
  }
  __syncthreads();   // sgeo ready (block-shared); the ONLY barrier

  const float cai0 = sgeo[0], cai1 = sgeo[1], cai2 = sgeo[2];

  // ---- software prefetch for step 0 ----
  int jn = nbr[i * 64 + half * 32 + w];
  float np0, np1;
  {
    const size_t pb = ((size_t)(i * 512 + jn)) * 128;
    if (isb) {
      np0 = __bfloat162float(((const bf16*)pair)[pb + 2 * lane]);
      np1 = __bfloat162float(((const bf16*)pair)[pb + 2 * lane + 1]);
    } else {
      float2 pp = ((const float2*)pair)[(pb >> 1) + lane];
      np0 = pp.x; np1 = pp.y;
    }
  }
  float nlj  = l0[jn * 32 + c];
  float ncax = CA[jn * 3 + 0], ncay = CA[jn * 3 + 1], ncaz = CA[jn * 3 + 2];

#pragma unroll 1
  for (int step = 0; step < 8; ++step) {
    const int j = jn;
    const float p0 = np0, p1 = np1, lj = nlj;
    const float cax = ncax, cay = ncay, caz = ncaz;

    // prefetch step+1
    if (step < 7) {
      jn = nbr[i * 64 + half * 32 + (step + 1) * 4 + w];
      const size_t pb = ((size_t)(i * 512 + jn)) * 128;
      if (isb) {
        np0 = __bfloat162float(((const bf16*)pair)[pb + 2 * lane]);
        np1 = __bfloat162float(((const bf16*)pair)[pb + 2 * lane + 1]);
      } else {
        float2 pp = ((const float2*)pair)[(pb >> 1) + lane];
        np0 = pp.x; np1 = pp.y;
      }
      nlj  = l0[jn * 32 + c];
      ncax = CA[jn * 3 + 0]; ncay = CA[jn * 3 + 1]; ncaz = CA[jn * 3 + 2];
    }

    // ---- pair-row LN (wave-wide stats) ----
    float S  = wsum64(p0 + p1);
    float Sq = wsum64(p0 * p0 + p1 * p1);
    float mu = S * (1.f / 128.f);
    float rs = rsqrtf(fmaxf(Sq * (1.f / 128.f) - mu * mu, 0.f) + 1e-5f);
    ped[w][2 * lane]     = (p0 - mu) * rs * gp0 + bp0;
    ped[w][2 * lane + 1] = (p1 - mu) * rs * gp1 + bp1;
    // wave-private LDS: compiler-inserted lgkmcnt orders write->read (r5-proven)

    // ---- e1 = LN(pe @ We1 + be1): broadcast float4 reads x register weights
    float acc = 0.f;
    {
      const float4* p4 = (const float4*)&ped[w][h * 64];
#pragma unroll
      for (int t = 0; t < 16; ++t) {
        float4 pv = p4[t];
        acc += pv.x * we1r[4 * t]     + pv.y * we1r[4 * t + 1]
             + pv.z * we1r[4 * t + 2] + pv.w * we1r[4 * t + 3];
      }
    }
    acc += __shfl_xor(acc, 32, 64);
    acc += be1c;
    float m2 = wsum64(acc) * (1.f / 64.f);                       // halves duplicated
    float r2 = rsqrtf(fmaxf(wsum64(acc * acc) * (1.f / 64.f) - m2 * m2, 0.f) + 1e-5f);
    float we = (acc - m2) * r2 * ge1c + bee1c;

    // ---- geometry ----
    float dex = cax - cai0, dey = cay - cai1, dez = caz - cai2;
    float dn  = sqrtf(dex * dex + dey * dey + dez * dez);
    float idn = 1.f / (dn + 1e-8f);
    float dux = dex * idn, duy = dey * idn, duz = dez * idn;

    if (h == 0) { sinv[w][32 + c] = lj; sinv[w][64 + c] = we; }
    if (lane == 0) {
      sinv[w][96] = dn;
      sinv[w][97] = sgeo[3] * dux + sgeo[4] * duy + sgeo[5] * duz;
      sinv[w][98] = sgeo[6] * dux + sgeo[7] * duy + sgeo[8] * duz;
      sinv[w][99] = sgeo[9] * dux + sgeo[10] * duy + sgeo[11] * duz;
    }

    // ---- m = gelu(inv @ W1 + b1) ----
    float a1 = 0.f;
    {
      const float4* i4 = (const float4*)&sinv[w][h * 52];
#pragma unroll
      for (int t = 0; t < 13; ++t) {
        float4 iv = i4[t];
        a1 += iv.x * w1r[4 * t]     + iv.y * w1r[4 * t + 1]
            + iv.z * w1r[4 * t + 2] + iv.w * w1r[4 * t + 3];
      }
    }
    a1 += __shfl_xor(a1, 32, 64);
    a1 += b1c;
    float u  = 0.7978845608028654f * (a1 + 0.044715f * a1 * a1 * a1);
    float mm = 0.5f * a1 * (1.f + tanhf(u));   // jax.nn.gelu approximate=True

    if (h == 0) atomicAdd(&agg[j * 32 + c], mm);

    // coef = m @ Wv (6 butterfly sums; halves duplicated -> x0.5)
    float co[6];
#pragma unroll
    for (int o = 0; o < 6; ++o) co[o] = 0.5f * wsum64(mm * wvr[o]);
    if (lane < 9) {
      int o = lane / 3, xx = lane % 3;
      float dcomp = (xx == 0) ? dex : ((xx == 1) ? dey : dez);
      atomicAdd(&v_agg[j * 9 + lane], co[o] * dcomp + co[3 + o] * sgeo[12 + o * 3 + xx]);
    }
  }
}

// ---------------------------------------------------------------------------
// Kernel 4: output heads. grid 512, block 64. (unchanged from r6)
// ---------------------------------------------------------------------------
__global__ __launch_bounds__(64) void k_out(
    const float* __restrict__ l0, const float* __restrict__ agg,
    const float* __restrict__ v, const float* __restrict__ v_agg,
    const float* __restrict__ CA,
    const void* __restrict__ W2, const void* __restrict__ b2,
    const void* __restrict__ Wself,
    const void* __restrict__ g_state, const void* __restrict__ b_state,
    const void* __restrict__ Wl, const void* __restrict__ bl,
    void* __restrict__ out)
{
  const bool isb = detect_bf16(g_state);
  const int l = blockIdx.x;
  const int lane = threadIdx.x;
  const int c = lane & 31, h = lane >> 5;
  __shared__ float scat[64], soff[9];
  if (lane < 32) { scat[lane] = l0[l * 32 + lane]; scat[32 + lane] = agg[l * 32 + lane]; }
  __syncthreads();

  // h_out = [l0, agg] @ W2 + b2 : lane (c,h), inner half each
  float acc = 0.f;
  {
    const int fb = h * 32;
    for (int f = 0; f < 32; ++f) acc += scat[fb + f] * ldf(W2, (fb + f) * 32 + c, isb);
  }
  acc += __shfl_xor(acc, 32, 64);
  acc += ldf(b2, c, isb);

  float mu = wsum64(acc) * (1.f / 64.f);
  float rs = rsqrtf(fmaxf(wsum64(acc * acc) * (1.f / 64.f) - mu * mu, 0.f) + 1e-5f);
  float hn = (acc - mu) * rs * ldf(g_state, c, isb) + ldf(b_state, c, isb);
  float pre = 0.5f * wsum64(hn * ldf(Wl, c, isb)) + ldf(bl, 0, isb);
  if (lane == 0) stf(out, 4608 + l, 1.f / (1.f + expf(-pre)), isb);

  if (lane < 9) {
    int o = lane / 3, xx = lane % 3;
    float s = v_agg[l * 9 + lane];
#pragma unroll
    for (int ii = 0; ii < 3; ++ii) s += ldf(Wself, ii * 3 + o, isb) * v[l * 9 + ii * 3 + xx];
    soff[lane] = s;
  }
  __syncthreads();
  if (lane < 9) {
    int xx = lane % 3;
    float add = (l == 0) ? 0.f : (CA[l * 3 + xx] + soff[3 + xx]);  // residue 0 zeroed
    stf(out, l * 9 + lane, soff[lane] + add, isb);
  }
}

extern "C" void kernel_launch(void* const* d_in, const int* in_sizes, int n_in,
                              void* d_out, int out_size, void* d_ws, size_t ws_size,
                              hipStream_t stream) {
  (void)in_sizes; (void)n_in; (void)out_size; (void)ws_size;
  const void* xyz     = d_in[0];
  const void* state   = d_in[1];
  const void* msa     = d_in[4];
  const void* pair    = d_in[5];
  const void* seq1hot = d_in[6];
  const void* g_msa   = d_in[10];
  const void* b_msa   = d_in[11];
  const void* g_pair  = d_in[12];
  const void* b_pair  = d_in[13];
  const void* g_state = d_in[14];
  const void* b_state = d_in[15];
  const void* g_node  = d_in[16];
  const void* b_node  = d_in[17];
  const void* g_e1    = d_in[18];
  const void* b_e1    = d_in[19];
  const void* Wx      = d_in[20];
  const void* bx      = d_in[21];
  const void* We1     = d_in[22];
  const void* be1     = d_in[23];
  const void* W1      = d_in[24];
  const void* b1      = d_in[25];
  const void* W2      = d_in[26];
  const void* b2      = d_in[27];
  const void* Wv      = d_in[28];
  const void* Wvv     = d_in[29];
  const void* Wself   = d_in[30];
  const void* Wl      = d_in[31];
  const void* bl      = d_in[32];

  float* ws    = (float*)d_ws;
  float* l0    = ws;            // 512*32
  float* CA    = ws + 16384;    // 512*3
  float* v     = ws + 17920;    // 512*9
  float* vproj = ws + 22528;    // 512*9
  float* agg   = ws + 27136;    // 512*32
  float* v_agg = ws + 43520;    // 512*9
  int*   nbr   = (int*)(ws + 48128);  // 512*64 ints

  hipLaunchKernelGGL(k_node, dim3(512), dim3(256), 0, stream,
                     xyz, state, msa, seq1hot, g_msa, b_msa, g_state, b_state,
                     g_node, b_node, Wx, bx, Wvv, l0, CA, v, vproj, agg, v_agg);
  hipLaunchKernelGGL(k_topk, dim3(512), dim3(256), 0, stream, CA, nbr);
  hipLaunchKernelGGL(k_edge, dim3(1024), dim3(256), 0, stream,
                     pair, g_pair, b_pair, We1, be1, g_e1, b_e1, W1, b1, Wv,
                     nbr, l0, CA, v, vproj, agg, v_agg);
  hipLaunchKernelGGL(k_out, dim3(512), dim3(64), 0, stream,
                     l0, agg, v, v_agg, CA, W2, b2, Wself, g_state, b_state, Wl, bl,
                     (void*)d_out);
}

// Round 8
// 308.965 us; speedup vs baseline: 1.2748x; 1.0006x over previous
//
#include <hip/hip_runtime.h>
#include <hip/hip_bf16.h>
#include <math.h>

typedef __hip_bfloat16 bf16;

// dtype: inputs are f32 (measured round 3), but keep runtime detect via the
// first 32-bit word of a ones-vector: f32 -> 0x3F800000, bf16 -> 0x3F803F80.
__device__ __forceinline__ bool detect_bf16(const void* ones_vec) {
  return ((const unsigned int*)ones_vec)[0] == 0x3F803F80u;
}
__device__ __forceinline__ float ldf(const void* p, long idx, bool isb) {
  if (isb) return __bfloat162float(((const bf16*)p)[idx]);
  return ((const float*)p)[idx];
}
__device__ __forceinline__ void stf(void* p, long idx, float v, bool isb) {
  if (isb) ((bf16*)p)[idx] = __float2bfloat16(v);
  else     ((float*)p)[idx] = v;
}
// butterfly sum across the full 64-lane wave
__device__ __forceinline__ float wsum64(float x) {
#pragma unroll
  for (int off = 32; off > 0; off >>= 1) x += __shfl_xor(x, off, 64);
  return x;
}
// butterfly sum within each 32-lane half (valid when halves hold identical
// per-c data, or when only lanes 0..31 carry payload)
__device__ __forceinline__ float wsum32(float x) {
#pragma unroll
  for (int off = 16; off > 0; off >>= 1) x += __shfl_xor(x, off, 64);
  return x;
}

// ---------------------------------------------------------------------------
// Kernel 1 (fused): per-node pipeline + top-64 NN selection for residue i.
// The topk part reads CA directly from xyz (CA = atom 1), so it has NO
// cross-block dependency on the node pipeline -- fusing removes the full
// grid drain that a separate k_topk dispatch required.
// grid 512, block 256.
// ---------------------------------------------------------------------------
__global__ __launch_bounds__(256) void k_node_topk(
    const void* __restrict__ xyz, const void* __restrict__ state,
    const void* __restrict__ msa, const void* __restrict__ seq1hot,
    const void* __restrict__ g_msa, const void* __restrict__ b_msa,
    const void* __restrict__ g_state, const void* __restrict__ b_state,
    const void* __restrict__ g_node, const void* __restrict__ b_node,
    const void* __restrict__ Wx, const void* __restrict__ bx,
    const void* __restrict__ Wvv,
    float* __restrict__ l0, float* __restrict__ CA, float* __restrict__ v,
    float* __restrict__ vproj, float* __restrict__ agg, float* __restrict__ v_agg,
    int* __restrict__ nbr)
{
  const bool isb = detect_bf16(g_msa);
  const int i = blockIdx.x;
  const int t = threadIdx.x;
  const int lane = t & 63, w = t >> 6;
  __shared__ float nin[312];
  __shared__ float wred[2][4];
  __shared__ float part[8][32];
  __shared__ float sxyz[9], sv9[9];
  __shared__ float cx[512], cy[512], cz[512];
  __shared__ unsigned long long key[512];

  // ---- stage all CAs from xyz (for topk; independent of node pipeline) ----
  for (int tt = t; tt < 512; tt += 256) {
    cx[tt] = ldf(xyz, tt * 9 + 3, isb);
    cy[tt] = ldf(xyz, tt * 9 + 4, isb);
    cz[tt] = ldf(xyz, tt * 9 + 5, isb);
  }

  // ---- msa LN (256): one element per thread ----
  float x = ldf(msa, i * 256 + t, isb);
  float s1 = wsum64(x), s2 = wsum64(x * x);
  if (lane == 0) { wred[0][w] = s1; wred[1][w] = s2; }
  if (t < 9) sxyz[t] = ldf(xyz, i * 9 + t, isb);
  __syncthreads();
  float S  = wred[0][0] + wred[0][1] + wred[0][2] + wred[0][3];
  float Sq = wred[1][0] + wred[1][1] + wred[1][2] + wred[1][3];
  float mu = S * (1.f / 256.f);
  float rs = rsqrtf(fmaxf(Sq * (1.f / 256.f) - mu * mu, 0.f) + 1e-5f);
  nin[t] = (x - mu) * rs * ldf(g_msa, t, isb) + ldf(b_msa, t, isb);
  if (t < 21) nin[256 + t] = ldf(seq1hot, i * 21 + t, isb);
  if (t < 3)  nin[309 + t] = 0.f;

  // ---- state LN (32): wave 0 only ----
  if (w == 0) {
    float sx  = (lane < 32) ? ldf(state, i * 32 + lane, isb) : 0.f;
    float Ss  = wsum64(sx), Ssq = wsum64(sx * sx);
    float mus = Ss * (1.f / 32.f);
    float rss = rsqrtf(fmaxf(Ssq * (1.f / 32.f) - mus * mus, 0.f) + 1e-5f);
    if (lane < 32)
      nin[277 + lane] = (sx - mus) * rss * ldf(g_state, lane, isb) + ldf(b_state, lane, isb);
  }
  __syncthreads();

  // ---- Wx GEMV: thread (c, g) handles rows f ≡ g (mod 8) ----
  const int c = t & 31, g = t >> 5;
  float acc = 0.f;
  for (int f = g; f < 309; f += 8) acc += nin[f] * ldf(Wx, f * 32 + c, isb);
  part[g][c] = acc;

  // ---- topk: distances + packed keys (cx ready since barrier 1) ----
  float xi = cx[i], yi = cy[i], zi = cz[i];
  for (int tt = t; tt < 512; tt += 256) {
    float dx = cx[tt] - xi, dy = cy[tt] - yi, dz = cz[tt] - zi;
    float d2 = dx * dx + dy * dy + dz * dz;
    unsigned int bits = (tt == i) ? 0x7f800000u : __float_as_uint(d2);  // diag -> +inf
    key[tt] = ((unsigned long long)bits << 32) | (unsigned int)tt;
  }
  __syncthreads();

  if (w == 0) {
    float a = 0.f;
    if (lane < 32) {
      a = ldf(bx, lane, isb);
#pragma unroll
      for (int gg = 0; gg < 8; ++gg) a += part[gg][lane];
    }
    float Sa = wsum32(a), Saq = wsum32(a * a);   // payload only in lanes 0..31
    float mn = Sa * (1.f / 32.f);
    float rn = rsqrtf(fmaxf(Saq * (1.f / 32.f) - mn * mn, 0.f) + 1e-5f);
    if (lane < 32)
      l0[i * 32 + lane] = (a - mn) * rn * ldf(g_node, lane, isb) + ldf(b_node, lane, isb);
  } else if (w == 1) {
    if (lane < 3) CA[i * 3 + lane] = sxyz[3 + lane];
    if (lane < 9) {
      float vv = sxyz[lane] - sxyz[3 + lane % 3];
      v[i * 9 + lane] = vv;
      sv9[lane] = vv;
    }
    if (lane < 32) agg[i * 32 + lane] = 0.f;
  } else if (w == 2) {
    if (lane < 9) v_agg[i * 9 + lane] = 0.f;
  }
  __syncthreads();
  if (w == 1 && lane < 9) {
    int o = lane / 3, xc = lane % 3;
    float s = 0.f;
#pragma unroll
    for (int ii = 0; ii < 3; ++ii) s += ldf(Wvv, ii * 3 + o, isb) * sv9[ii * 3 + xc];
    vproj[i * 9 + lane] = s;
  }

  // ---- bitonic sort of 512 keys; lowest 64 -> nbr ----
  for (int k = 2; k <= 512; k <<= 1) {
    for (int j = k >> 1; j > 0; j >>= 1) {
      __syncthreads();
      int tt  = threadIdx.x;
      int i0 = ((tt & ~(j - 1)) << 1) | (tt & (j - 1));
      int i1 = i0 | j;
      bool up = ((i0 & k) == 0);
      unsigned long long a = key[i0], b = key[i1];
      if ((a > b) == up) { key[i0] = b; key[i1] = a; }
    }
  }
  __syncthreads();
  if (threadIdx.x < 64)
    nbr[i * 64 + threadIdx.x] = (int)(key[threadIdx.x] & 0xffffffffu);
}

// ---------------------------------------------------------------------------
// Kernel 3 (v3.1): per-edge messages + scatter. 1024 blocks (i, half), 4
// waves, 8 edges/wave. Weights in registers; ped/sinv wave-private LDS;
// `#pragma unroll 1` prevents the r5 cross-step spill explosion; software
// prefetch of next edge. wsum32 used where halves carry duplicated data.
// ---------------------------------------------------------------------------
__global__ __launch_bounds__(256) void k_edge(
    const void* __restrict__ pair,
    const void* __restrict__ g_pair, const void* __restrict__ b_pair,
    const void* __restrict__ We1, const void* __restrict__ be1,
    const void* __restrict__ g_e1, const void* __restrict__ b_e1,
    const void* __restrict__ W1, const void* __restrict__ b1,
    const void* __restrict__ Wv,
    const int* __restrict__ nbr,
    const float* __restrict__ l0, const float* __restrict__ CA,
    const float* __restrict__ v, const float* __restrict__ vproj,
    float* __restrict__ agg, float* __restrict__ v_agg)
{
  const bool isb = detect_bf16(g_pair);
  __shared__ float ped[4][128];
  __shared__ float sinv[4][104];
  __shared__ float sgeo[21];   // CAi[3], vi[9], vpi[9]

  const int i    = blockIdx.x >> 1;
  const int half = blockIdx.x & 1;
  const int tid  = threadIdx.x;
  const int w = tid >> 6, lane = tid & 63;
  const int c = lane & 31, h = lane >> 5;

  if (tid < 3)  sgeo[tid] = CA[i * 3 + tid];
  else if (tid < 12) sgeo[tid] = v[i * 9 + (tid - 3)];
  else if (tid < 21) sgeo[tid] = vproj[i * 9 + (tid - 12)];

  // ---- loop-invariant per-lane registers ----
  float we1r[64];
#pragma unroll
  for (int t = 0; t < 64; ++t) we1r[t] = ldf(We1, (h * 64 + t) * 32 + c, isb);
  float w1r[52];
#pragma unroll
  for (int t = 0; t < 52; ++t) {
    int f = h * 52 + t;
    w1r[t] = (f < 100) ? ldf(W1, f * 32 + c, isb) : 0.f;
  }
  const float gp0 = ldf(g_pair, 2 * lane, isb),     gp1 = ldf(g_pair, 2 * lane + 1, isb);
  const float bp0 = ldf(b_pair, 2 * lane, isb),     bp1 = ldf(b_pair, 2 * lane + 1, isb);
  const float be1c = ldf(be1, c, isb), ge1c = ldf(g_e1, c, isb);
  const float bee1c = ldf(b_e1, c, isb), b1c = ldf(b1, c, isb);
  float wvr[6];
#pragma unroll
  for (int o = 0; o < 6; ++o) wvr[o] = ldf(Wv, c * 6 + o, isb);

  if (h == 0) {
    sinv[w][c] = l0[i * 32 + c];
    if (c < 4) sinv[w][100 + c] = 0.f;
  }
  __syncthreads();   // sgeo ready (block-shared); the ONLY barrier

  const float cai0 = sgeo[0], cai1 = sgeo[1], cai2 = sgeo[2];

  // ---- software prefetch for step 0 ----
  int jn = nbr[i * 64 + half * 32 + w];
  float np0, np1;
  {
    const size_t pb = ((size_t)(i * 512 + jn)) * 128;
    if (isb) {
      np0 = __bfloat162float(((const bf16*)pair)[pb + 2 * lane]);
      np1 = __bfloat162float(((const bf16*)pair)[pb + 2 * lane + 1]);
    } else {
      float2 pp = ((const float2*)pair)[(pb >> 1) + lane];
      np0 = pp.x; np1 = pp.y;
    }
  }
  float nlj  = l0[jn * 32 + c];
  float ncax = CA[jn * 3 + 0], ncay = CA[jn * 3 + 1], ncaz = CA[jn * 3 + 2];

#pragma unroll 1
  for (int step = 0; step < 8; ++step) {
    const int j = jn;
    const float p0 = np0, p1 = np1, lj = nlj;
    const float cax = ncax, cay = ncay, caz = ncaz;

    // prefetch step+1
    if (step < 7) {
      jn = nbr[i * 64 + half * 32 + (step + 1) * 4 + w];
      const size_t pb = ((size_t)(i * 512 + jn)) * 128;
      if (isb) {
        np0 = __bfloat162float(((const bf16*)pair)[pb + 2 * lane]);
        np1 = __bfloat162float(((const bf16*)pair)[pb + 2 * lane + 1]);
      } else {
        float2 pp = ((const float2*)pair)[(pb >> 1) + lane];
        np0 = pp.x; np1 = pp.y;
      }
      nlj  = l0[jn * 32 + c];
      ncax = CA[jn * 3 + 0]; ncay = CA[jn * 3 + 1]; ncaz = CA[jn * 3 + 2];
    }

    // ---- pair-row LN (full-wave stats; ped distributed across 64 lanes) ----
    float S  = wsum64(p0 + p1);
    float Sq = wsum64(p0 * p0 + p1 * p1);
    float mu = S * (1.f / 128.f);
    float rs = rsqrtf(fmaxf(Sq * (1.f / 128.f) - mu * mu, 0.f) + 1e-5f);
    ped[w][2 * lane]     = (p0 - mu) * rs * gp0 + bp0;
    ped[w][2 * lane + 1] = (p1 - mu) * rs * gp1 + bp1;
    // wave-private LDS: compiler-inserted lgkmcnt orders write->read (r5-proven)

    // ---- e1 = LN(pe @ We1 + be1): broadcast float4 reads x register weights
    float acc = 0.f;
    {
      const float4* p4 = (const float4*)&ped[w][h * 64];
#pragma unroll
      for (int t = 0; t < 16; ++t) {
        float4 pv = p4[t];
        acc += pv.x * we1r[4 * t]     + pv.y * we1r[4 * t + 1]
             + pv.z * we1r[4 * t + 2] + pv.w * we1r[4 * t + 3];
      }
    }
    acc += __shfl_xor(acc, 32, 64);   // halves now duplicated per c
    acc += be1c;
    float m2 = wsum32(acc) * (1.f / 32.f);
    float r2 = rsqrtf(fmaxf(wsum32(acc * acc) * (1.f / 32.f) - m2 * m2, 0.f) + 1e-5f);
    float we = (acc - m2) * r2 * ge1c + bee1c;

    // ---- geometry ----
    float dex = cax - cai0, dey = cay - cai1, dez = caz - cai2;
    float dn  = sqrtf(dex * dex + dey * dey + dez * dez);
    float idn = 1.f / (dn + 1e-8f);
    float dux = dex * idn, duy = dey * idn, duz = dez * idn;

    if (h == 0) { sinv[w][32 + c] = lj; sinv[w][64 + c] = we; }
    if (lane == 0) {
      sinv[w][96] = dn;
      sinv[w][97] = sgeo[3] * dux + sgeo[4] * duy + sgeo[5] * duz;
      sinv[w][98] = sgeo[6] * dux + sgeo[7] * duy + sgeo[8] * duz;
      sinv[w][99] = sgeo[9] * dux + sgeo[10] * duy + sgeo[11] * duz;
    }

    // ---- m = gelu(inv @ W1 + b1) ----
    float a1 = 0.f;
    {
      const float4* i4 = (const float4*)&sinv[w][h * 52];
#pragma unroll
      for (int t = 0; t < 13; ++t) {
        float4 iv = i4[t];
        a1 += iv.x * w1r[4 * t]     + iv.y * w1r[4 * t + 1]
            + iv.z * w1r[4 * t + 2] + iv.w * w1r[4 * t + 3];
      }
    }
    a1 += __shfl_xor(a1, 32, 64);
    a1 += b1c;
    float u  = 0.7978845608028654f * (a1 + 0.044715f * a1 * a1 * a1);
    float mm = 0.5f * a1 * (1.f + tanhf(u));   // jax.nn.gelu approximate=True

    if (h == 0) atomicAdd(&agg[j * 32 + c], mm);

    // coef = m @ Wv (6 half-wave butterflies; mm duplicated across halves)
    float co[6];
#pragma unroll
    for (int o = 0; o < 6; ++o) co[o] = wsum32(mm * wvr[o]);
    if (lane < 9) {
      int o = lane / 3, xx = lane % 3;
      float dcomp = (xx == 0) ? dex : ((xx == 1) ? dey : dez);
      atomicAdd(&v_agg[j * 9 + lane], co[o] * dcomp + co[3 + o] * sgeo[12 + o * 3 + xx]);
    }
  }
}

// ---------------------------------------------------------------------------
// Kernel 4: output heads. grid 512, block 64. (unchanged)
// ---------------------------------------------------------------------------
__global__ __launch_bounds__(64) void k_out(
    const float* __restrict__ l0, const float* __restrict__ agg,
    const float* __restrict__ v, const float* __restrict__ v_agg,
    const float* __restrict__ CA,
    const void* __restrict__ W2, const void* __restrict__ b2,
    const void* __restrict__ Wself,
    const void* __restrict__ g_state, const void* __restrict__ b_state,
    const void* __restrict__ Wl, const void* __restrict__ bl,
    void* __restrict__ out)
{
  const bool isb = detect_bf16(g_state);
  const int l = blockIdx.x;
  const int lane = threadIdx.x;
  const int c = lane & 31, h = lane >> 5;
  __shared__ float scat[64], soff[9];
  if (lane < 32) { scat[lane] = l0[l * 32 + lane]; scat[32 + lane] = agg[l * 32 + lane]; }
  __syncthreads();

  // h_out = [l0, agg] @ W2 + b2 : lane (c,h), inner half each
  float acc = 0.f;
  {
    const int fb = h * 32;
    for (int f = 0; f < 32; ++f) acc += scat[fb + f] * ldf(W2, (fb + f) * 32 + c, isb);
  }
  acc += __shfl_xor(acc, 32, 64);
  acc += ldf(b2, c, isb);

  float mu = wsum32(acc) * (1.f / 32.f);
  float rs = rsqrtf(fmaxf(wsum32(acc * acc) * (1.f / 32.f) - mu * mu, 0.f) + 1e-5f);
  float hn = (acc - mu) * rs * ldf(g_state, c, isb) + ldf(b_state, c, isb);
  float pre = wsum32(hn * ldf(Wl, c, isb)) + ldf(bl, 0, isb);
  if (lane == 0) stf(out, 4608 + l, 1.f / (1.f + expf(-pre)), isb);

  if (lane < 9) {
    int o = lane / 3, xx = lane % 3;
    float s = v_agg[l * 9 + lane];
#pragma unroll
    for (int ii = 0; ii < 3; ++ii) s += ldf(Wself, ii * 3 + o, isb) * v[l * 9 + ii * 3 + xx];
    soff[lane] = s;
  }
  __syncthreads();
  if (lane < 9) {
    int xx = lane % 3;
    float add = (l == 0) ? 0.f : (CA[l * 3 + xx] + soff[3 + xx]);  // residue 0 zeroed
    stf(out, l * 9 + lane, soff[lane] + add, isb);
  }
}

extern "C" void kernel_launch(void* const* d_in, const int* in_sizes, int n_in,
                              void* d_out, int out_size, void* d_ws, size_t ws_size,
                              hipStream_t stream) {
  (void)in_sizes; (void)n_in; (void)out_size; (void)ws_size;
  const void* xyz     = d_in[0];
  const void* state   = d_in[1];
  const void* msa     = d_in[4];
  const void* pair    = d_in[5];
  const void* seq1hot = d_in[6];
  const void* g_msa   = d_in[10];
  const void* b_msa   = d_in[11];
  const void* g_pair  = d_in[12];
  const void* b_pair  = d_in[13];
  const void* g_state = d_in[14];
  const void* b_state = d_in[15];
  const void* g_node  = d_in[16];
  const void* b_node  = d_in[17];
  const void* g_e1    = d_in[18];
  const void* b_e1    = d_in[19];
  const void* Wx      = d_in[20];
  const void* bx      = d_in[21];
  const void* We1     = d_in[22];
  const void* be1     = d_in[23];
  const void* W1      = d_in[24];
  const void* b1      = d_in[25];
  const void* W2      = d_in[26];
  const void* b2      = d_in[27];
  const void* Wv      = d_in[28];
  const void* Wvv     = d_in[29];
  const void* Wself   = d_in[30];
  const void* Wl      = d_in[31];
  const void* bl      = d_in[32];

  float* ws    = (float*)d_ws;
  float* l0    = ws;            // 512*32
  float* CA    = ws + 16384;    // 512*3
  float* v     = ws + 17920;    // 512*9
  float* vproj = ws + 22528;    // 512*9
  float* agg   = ws + 27136;    // 512*32
  float* v_agg = ws + 43520;    // 512*9
  int*   nbr   = (int*)(ws + 48128);  // 512*64 ints

  hipLaunchKernelGGL(k_node_topk, dim3(512), dim3(256), 0, stream,
                     xyz, state, msa, seq1hot, g_msa, b_msa, g_state, b_state,
                     g_node, b_node, Wx, bx, Wvv, l0, CA, v, vproj, agg, v_agg, nbr);
  hipLaunchKernelGGL(k_edge, dim3(1024), dim3(256), 0, stream,
                     pair, g_pair, b_pair, We1, be1, g_e1, b_e1, W1, b1, Wv,
                     nbr, l0, CA, v, vproj, agg, v_agg);
  hipLaunchKernelGGL(k_out, dim3(512), dim3(64), 0, stream,
                     l0, agg, v, v_agg, CA, W2, b2, Wself, g_state, b_state, Wl, bl,
                     (void*)d_out);
}